// Round 3
// baseline (1438.859 us; speedup 1.0000x reference)
//
#include <hip/hip_runtime.h>
#include <hip/hip_cooperative_groups.h>
#include <hip/hip_bf16.h>
#include <cstdint>
#include <cstddef>

namespace cg = cooperative_groups;

#define DDIM 1024
#define BROWS 32768

typedef __attribute__((ext_vector_type(8))) short short8;
typedef __attribute__((ext_vector_type(4))) float floatx4;

__device__ __forceinline__ float bf2f(unsigned short u) {
  return __uint_as_float(((unsigned int)u) << 16);
}
__device__ __forceinline__ unsigned short f2bf(float f) {
  unsigned int u = __float_as_uint(f);
  u += 0x7FFFu + ((u >> 16) & 1u);
  return (unsigned short)(u >> 16);
}

__device__ __forceinline__ void load_lds16(const void* g, void* l) {
  __builtin_amdgcn_global_load_lds(
      (const __attribute__((address_space(1))) unsigned int*)g,
      (__attribute__((address_space(3))) unsigned int*)l,
      16, 0, 0);
}

// ===========================================================================
// Big GEMM: Out = (x @ W) * inv + bias.  A f32 (reg-prefetch + cvt), B bf16
// (global_load_lds), double-buffered LDS, 128x128 tile BK=32, LDS epilogue.
// ===========================================================================
__global__ void __launch_bounds__(256, 2)
big_gemm(const float* __restrict__ Af, const unsigned short* __restrict__ Bt,
         float* __restrict__ Outf, const float* __restrict__ inv_ptr,
         const float* __restrict__ bias)
{
  __shared__ __align__(16) char smem[33280];
  // As buffers: [0,8192), [8192,16384); Bs buffers: [16384,24576), [24576,32768)
  float* epi = (float*)smem;  // epilogue alias, 16896 B

  const int tid  = threadIdx.x;
  const int lane = tid & 63;
  const int wid  = tid >> 6;
  const int wr = wid >> 1, wc = wid & 1;
  const int g = lane >> 4, r = lane & 15;

  const int bn0 = (int)(blockIdx.x & 7) * 128;
  const int bm0 = (int)(blockIdx.x >> 3) * 128;

  // staging geometry: thread covers (row = strow [+64], cols stcol..stcol+7)
  const int strow = tid >> 2;
  const int stcol = (tid & 3) * 8;
  const float* aB0 = Af + (size_t)(bm0 + strow) * DDIM + stcol;
  const float* aB1 = Af + (size_t)(bm0 + 64 + strow) * DDIM + stcol;
  const unsigned short* bB0 = Bt + (size_t)(bn0 + strow) * DDIM + stcol;
  const unsigned short* bB1 = Bt + (size_t)(bn0 + 64 + strow) * DDIM + stcol;

  const floatx4 zero4 = {0.f, 0.f, 0.f, 0.f};
  floatx4 acc[4][4];
#pragma unroll
  for (int m = 0; m < 4; ++m)
#pragma unroll
    for (int n = 0; n < 4; ++n) acc[m][n] = zero4;

  // prologue: stage K-tile 0 into buffer 0
  {
    load_lds16(bB0, smem + 16384 + tid * 16);
    load_lds16(bB1, smem + 16384 + 4096 + tid * 16);
    float4 n0 = *(const float4*)aB0;
    float4 n1 = *(const float4*)(aB0 + 4);
    float4 n2 = *(const float4*)aB1;
    float4 n3 = *(const float4*)(aB1 + 4);
    short8 t0, t1;
    t0[0] = (short)f2bf(n0.x); t0[1] = (short)f2bf(n0.y);
    t0[2] = (short)f2bf(n0.z); t0[3] = (short)f2bf(n0.w);
    t0[4] = (short)f2bf(n1.x); t0[5] = (short)f2bf(n1.y);
    t0[6] = (short)f2bf(n1.z); t0[7] = (short)f2bf(n1.w);
    t1[0] = (short)f2bf(n2.x); t1[1] = (short)f2bf(n2.y);
    t1[2] = (short)f2bf(n2.z); t1[3] = (short)f2bf(n2.w);
    t1[4] = (short)f2bf(n3.x); t1[5] = (short)f2bf(n3.y);
    t1[6] = (short)f2bf(n3.z); t1[7] = (short)f2bf(n3.w);
    *(short8*)(smem + tid * 16) = t0;
    *(short8*)(smem + 4096 + tid * 16) = t1;
  }
  __syncthreads();

  for (int t = 0; t < 32; ++t) {
    const int co = (t & 1) << 13;         // 0 / 8192
    char* curA = smem + co;
    char* curB = smem + 16384 + co;
    char* nxtA = smem + (co ^ 8192);
    char* nxtB = smem + 16384 + (co ^ 8192);

    float4 n0, n1, n2, n3;
    const bool pref = (t < 31);
    if (pref) {
      const int ko = (t + 1) * 32;
      n0 = *(const float4*)(aB0 + ko);          // issued early, consumed late
      n1 = *(const float4*)(aB0 + ko + 4);
      n2 = *(const float4*)(aB1 + ko);
      n3 = *(const float4*)(aB1 + ko + 4);
      load_lds16(bB0 + ko, nxtB + tid * 16);
      load_lds16(bB1 + ko, nxtB + 4096 + tid * 16);
    }

    short8 afr[4], bfr[4];
#pragma unroll
    for (int m = 0; m < 4; ++m)
      afr[m] = *(const short8*)(curA + (wr * 64 + m * 16 + r) * 64 + g * 16);
#pragma unroll
    for (int n = 0; n < 4; ++n)
      bfr[n] = *(const short8*)(curB + (wc * 64 + n * 16 + r) * 64 + g * 16);
#pragma unroll
    for (int m = 0; m < 4; ++m)
#pragma unroll
      for (int n = 0; n < 4; ++n)
        acc[m][n] = __builtin_amdgcn_mfma_f32_16x16x32_bf16(afr[m], bfr[n], acc[m][n], 0, 0, 0);

    if (pref) {
      short8 t0, t1;
      t0[0] = (short)f2bf(n0.x); t0[1] = (short)f2bf(n0.y);
      t0[2] = (short)f2bf(n0.z); t0[3] = (short)f2bf(n0.w);
      t0[4] = (short)f2bf(n1.x); t0[5] = (short)f2bf(n1.y);
      t0[6] = (short)f2bf(n1.z); t0[7] = (short)f2bf(n1.w);
      t1[0] = (short)f2bf(n2.x); t1[1] = (short)f2bf(n2.y);
      t1[2] = (short)f2bf(n2.z); t1[3] = (short)f2bf(n2.w);
      t1[4] = (short)f2bf(n3.x); t1[5] = (short)f2bf(n3.y);
      t1[6] = (short)f2bf(n3.z); t1[7] = (short)f2bf(n3.w);
      *(short8*)(nxtA + tid * 16) = t0;
      *(short8*)(nxtA + 4096 + tid * 16) = t1;
    }
    __syncthreads();  // drains gload_lds (nxtB) + ds_writes (nxtA)
  }

  // Epilogue: stage 32x128 f32 chunks in LDS, store 64B/thread contiguous.
  const float inv = *inv_ptr;
  float bv[4];
#pragma unroll
  for (int n = 0; n < 4; ++n) bv[n] = bias[bn0 + wc * 64 + n * 16 + r];

#pragma unroll
  for (int m = 0; m < 4; ++m) {
    __syncthreads();
#pragma unroll
    for (int n = 0; n < 4; ++n)
#pragma unroll
      for (int q = 0; q < 4; ++q)
        epi[(wr * 16 + g * 4 + q) * 132 + wc * 64 + n * 16 + r] =
            acc[m][n][q] * inv + bv[n];
    __syncthreads();
    const int lrow = tid >> 3;
    const int lc0  = (tid & 7) * 16;
    const int grow = bm0 + m * 16 + (lrow & 15) + (lrow >> 4) * 64;
    float4* dst = (float4*)(Outf + (size_t)grow * DDIM + bn0 + lc0);
    const float4* sv = (const float4*)(epi + lrow * 132 + lc0);
    dst[0] = sv[0]; dst[1] = sv[1]; dst[2] = sv[2]; dst[3] = sv[3];
  }
}

// ===========================================================================
// Power-iteration chain as phases of one (cooperative) kernel, grid = 1024.
// ===========================================================================

// 32x32-tile 1024^3 bf16 GEMM step (C = A * Bt^T), verified in round 2.
__device__ __forceinline__ void sq_tile(const unsigned short* A, const unsigned short* Bt,
    unsigned short* Out, float* in_max, float* out_max,
    unsigned short* As, unsigned short* Bs, float* redw, int tid, int bid)
{
  const int lane = tid & 63, wid = tid >> 6;
  const int wr = wid >> 1, wc = wid & 1;
  const int g = lane >> 4, r = lane & 15;
  const int bm0 = (bid >> 5) * 32;
  const int bn0 = (bid & 31) * 32;

  const int so   = tid * 16;
  const int srow = so >> 7;
  const int sc16 = (so >> 4) & 7;
  const int scs  = sc16 ^ (srow & 7);
  const unsigned short* aSrc = A  + (size_t)(bm0 + srow) * DDIM + scs * 8;
  const unsigned short* bSrc = Bt + (size_t)(bn0 + srow) * DDIM + scs * 8;

  floatx4 acc = {0.f, 0.f, 0.f, 0.f};
  load_lds16(aSrc, (char*)As + so);
  load_lds16(bSrc, (char*)Bs + so);
  __syncthreads();

  const int arow = wr * 16 + r, brow = wc * 16 + r;
  int bufo = 0;
  for (int t = 0; t < 16; ++t) {
    if (t + 1 < 16) {
      const int kk = (t + 1) * 64;
      load_lds16(aSrc + kk, (char*)As + (bufo ^ 4096) + so);
      load_lds16(bSrc + kk, (char*)Bs + (bufo ^ 4096) + so);
    }
#pragma unroll
    for (int ks = 0; ks < 2; ++ks) {
      const int chunk = ((ks << 2) + g) ^ (r & 7);
      short8 af = *(const short8*)((const char*)As + bufo + (arow << 7) + (chunk << 4));
      short8 bf = *(const short8*)((const char*)Bs + bufo + (brow << 7) + (chunk << 4));
      acc = __builtin_amdgcn_mfma_f32_16x16x32_bf16(af, bf, acc, 0, 0, 0);
    }
    __syncthreads();
    bufo ^= 4096;
  }

  float c = 1.0f;
  if (in_max != nullptr) {
    // device-scope atomic load (L1-bypass) of the previous phase's max
    float mv = __uint_as_float(atomicMax((unsigned int*)in_max, 0u));
    int e; (void)frexpf(mv, &e);
    c = ldexpf(1.0f, -e);  // exact power of two
  }
  const float c2 = c * c;
  float lmax = 0.0f;
  const int ocol = bn0 + wc * 16 + r;
#pragma unroll
  for (int q = 0; q < 4; ++q) {
    const int orow = bm0 + wr * 16 + g * 4 + q;
    float v = acc[q] * c2;
    Out[(size_t)orow * DDIM + ocol] = f2bf(v);
    lmax = fmaxf(lmax, fabsf(v));
  }
#pragma unroll
  for (int off = 32; off > 0; off >>= 1) lmax = fmaxf(lmax, __shfl_down(lmax, off));
  if (lane == 0) redw[wid] = lmax;
  __syncthreads();
  if (tid == 0) {
    float m = fmaxf(fmaxf(redw[0], redw[1]), fmaxf(redw[2], redw[3]));
    atomicMax((unsigned int*)out_max, __float_as_uint(m));
  }
}

// vout[row] = 2^-12 * dot(P[row,:], vin)   (one row per block)
__device__ __forceinline__ void gemv_row(const unsigned short* P, const float* vin,
                                         float* vout, float* red, int tid, int row)
{
  const unsigned short* pr = P + (size_t)row * DDIM + (tid << 2);
  const uint2 pp = *(const uint2*)pr;
  const float4 vv = *(const float4*)(vin + (tid << 2));
  float s = bf2f((unsigned short)(pp.x & 0xFFFFu)) * vv.x
          + bf2f((unsigned short)(pp.x >> 16))     * vv.y
          + bf2f((unsigned short)(pp.y & 0xFFFFu)) * vv.z
          + bf2f((unsigned short)(pp.y >> 16))     * vv.w;
  red[tid] = s;
  __syncthreads();
  for (int st = 128; st > 0; st >>= 1) {
    if (tid < st) red[tid] += red[tid + st];
    __syncthreads();
  }
  if (tid == 0) vout[row] = red[0] * 0x1p-12f;
}

// Phases: 0 transpose | 1 M=WtW | 2 M^2 (+gemv u0*M) | 3 M^4 | 4 M^8 | 5 M^16
// | 6 M^32 | 7 M^64 (+gemv *M^32) | 8 gemv *M^64 (exp 97) | 9 v | 10 t | 11 fin
// vpart aliases ub (dead after phase 8).
__device__ void run_phase(int ph, const float* W, const float* u0v,
                          unsigned short* WT, unsigned short* P0, unsigned short* P1,
                          float* scal, float* ua, float* ub, float* vun, float* tpart,
                          int bid, int tid)
{
  __shared__ __align__(16) char CL[16768];
  unsigned short* As = (unsigned short*)CL;          // sq: [2][2048] = 8 KB
  unsigned short* Bs = (unsigned short*)(CL + 8192); // sq: 8 KB
  float* red  = (float*)CL;                          // alias (reductions/tiles)
  float* redw = (float*)(CL + 16384);

  switch (ph) {
    case 0: {  // WT[n][k] = bf16(W[k][n]), 32x32 tiles
      float* tile = (float*)CL;  // [32][33]
      const int kt = bid & 31, nt = bid >> 5;
      const int c = tid & 31, r0 = tid >> 5;
#pragma unroll
      for (int p = 0; p < 4; ++p) {
        const int kr = p * 8 + r0;
        tile[kr * 33 + c] = W[(size_t)(kt * 32 + kr) * DDIM + nt * 32 + c];
      }
      __syncthreads();
#pragma unroll
      for (int p = 0; p < 4; ++p) {
        const int nr = p * 8 + r0;
        WT[(size_t)(nt * 32 + nr) * DDIM + kt * 32 + c] = f2bf(tile[c * 33 + nr]);
      }
      break;
    }
    case 1: sq_tile(WT, WT, P0, nullptr, scal + 0, As, Bs, redw, tid, bid); break;
    case 2:
      sq_tile(P0, P0, P1, scal + 0, scal + 1, As, Bs, redw, tid, bid);
      __syncthreads();
      gemv_row(P0, u0v, ua, red, tid, bid);
      break;
    case 3: sq_tile(P1, P1, P0, scal + 1, scal + 2, As, Bs, redw, tid, bid); break;
    case 4: sq_tile(P0, P0, P1, scal + 2, scal + 3, As, Bs, redw, tid, bid); break;
    case 5: sq_tile(P1, P1, P0, scal + 3, scal + 4, As, Bs, redw, tid, bid); break;
    case 6: sq_tile(P0, P0, P1, scal + 4, scal + 5, As, Bs, redw, tid, bid); break;
    case 7:
      sq_tile(P1, P1, P0, scal + 5, scal + 6, As, Bs, redw, tid, bid);
      __syncthreads();
      gemv_row(P1, ua, ub, red, tid, bid);   // exp 1 -> 33
      break;
    case 8: gemv_row(P0, ub, ua, red, tid, bid); break;  // exp 33 -> 97
    case 9: {  // vun[row] = dot(W[row,:], ua); vpart(=ub)[row] = s^2
      const float4 wv = *(const float4*)(W + (size_t)bid * DDIM + (tid << 2));
      const float4 dv = *(const float4*)(ua + (tid << 2));
      float s = wv.x * dv.x + wv.y * dv.y + wv.z * dv.z + wv.w * dv.w;
      red[tid] = s;
      __syncthreads();
      for (int st = 128; st > 0; st >>= 1) {
        if (tid < st) red[tid] += red[tid + st];
        __syncthreads();
      }
      if (tid == 0) { float S = red[0]; vun[bid] = S; ub[bid] = S * S; }
      break;
    }
    case 10: {  // t[col] = dot(vun, W[:,col]); tpart per 32-col block
      if (bid < 32) {
        float* part = (float*)CL;  // [8][33]
        const int col = bid * 32 + (tid & 31);
        const int ch = tid >> 5;
        float s = 0.f;
        const int i0 = ch * 128;
        for (int i = i0; i < i0 + 128; ++i)
          s += vun[i] * W[(size_t)i * DDIM + col];
        part[ch * 33 + (tid & 31)] = s;
        __syncthreads();
        if (tid < 32) {
          float t = 0.f;
#pragma unroll
          for (int c2 = 0; c2 < 8; ++c2) t += part[c2 * 33 + tid];
          part[tid] = t * t;
        }
        __syncthreads();
        if (tid == 0) {
          float ss = 0.f;
#pragma unroll
          for (int c = 0; c < 32; ++c) ss += part[c];
          tpart[bid] = ss;
        }
      }
      break;
    }
    case 11: {  // sigma = sqrt(sum t^2 / sum v^2); inv = min(1, 0.9/sigma)
      if (bid == 0) {
        float s = ub[tid * 4] + ub[tid * 4 + 1] + ub[tid * 4 + 2] + ub[tid * 4 + 3];
        red[tid] = s;
        __syncthreads();
        for (int st = 128; st > 0; st >>= 1) {
          if (tid < st) red[tid] += red[tid + st];
          __syncthreads();
        }
        if (tid == 0) {
          float sv = red[0], st = 0.f;
          for (int i = 0; i < 32; ++i) st += tpart[i];
          float sigma = sqrtf(st / sv);
          scal[8] = (sigma > 0.9f) ? (0.9f / sigma) : 1.0f;
        }
      }
      break;
    }
  }
}

__global__ void __launch_bounds__(256, 4)
chain_coop(const float* W, const float* u0v, unsigned short* WT,
           unsigned short* P0, unsigned short* P1, float* scal,
           float* ua, float* ub, float* vun, float* tpart)
{
  cg::grid_group grid = cg::this_grid();
  for (int ph = 0; ph < 12; ++ph) {
    run_phase(ph, W, u0v, WT, P0, P1, scal, ua, ub, vun, tpart,
              (int)blockIdx.x, (int)threadIdx.x);
    if (ph < 11) grid.sync();
  }
}

__global__ void __launch_bounds__(256, 4)
chain_phase(int ph, const float* W, const float* u0v, unsigned short* WT,
            unsigned short* P0, unsigned short* P1, float* scal,
            float* ua, float* ub, float* vun, float* tpart)
{
  run_phase(ph, W, u0v, WT, P0, P1, scal, ua, ub, vun, tpart,
            (int)blockIdx.x, (int)threadIdx.x);
}

extern "C" void kernel_launch(void* const* d_in, const int* in_sizes, int n_in,
                              void* d_out, int out_size, void* d_ws, size_t ws_size,
                              hipStream_t stream)
{
  const float* x  = (const float*)d_in[0];
  const float* w  = (const float*)d_in[1];
  const float* b  = (const float*)d_in[2];
  const float* u0 = (const float*)d_in[3];
  float* out = (float*)d_out;

  char* ws = (char*)d_ws;
  float* scal = (float*)ws;                 // [0..6] max chain, [8] inv
  float* tpart = scal + 64;                 // 32 floats
  float* ua   = (float*)(ws + 0x1000);
  float* ub   = (float*)(ws + 0x2000);      // also vpart (alias, after phase 8)
  float* vun  = (float*)(ws + 0x3000);
  unsigned short* WT = (unsigned short*)(ws + 0x4000);
  unsigned short* P0 = (unsigned short*)(ws + 0x204000);
  unsigned short* P1 = (unsigned short*)(ws + 0x404000);

  hipMemsetAsync(d_ws, 0, 4096, stream);

  const float* Wp = w; const float* u0p = u0;
  unsigned short* WTp = WT; unsigned short* P0p = P0; unsigned short* P1p = P1;
  float* scalp = scal; float* uap = ua; float* ubp = ub; float* vunp = vun;
  float* tpartp = tpart;
  void* cargs[] = {&Wp, &u0p, &WTp, &P0p, &P1p, &scalp, &uap, &ubp, &vunp, &tpartp};
  hipError_t ce = hipLaunchCooperativeKernel((const void*)chain_coop,
                                             dim3(1024), dim3(256), cargs, 0, stream);
  if (ce != hipSuccess) {
    // fallback: identical phases as 12 sequential plain launches
    for (int ph = 0; ph < 12; ++ph)
      hipLaunchKernelGGL(chain_phase, dim3(1024), dim3(256), 0, stream,
                         ph, w, u0, WT, P0, P1, scal, ua, ub, vun, tpart);
  }

  hipLaunchKernelGGL(big_gemm, dim3(2048), dim3(256), 0, stream,
                     x, WT, out, &scal[8], b);
}

// Round 4
// 340.781 us; speedup vs baseline: 4.2222x; 4.2222x over previous
//
#include <hip/hip_runtime.h>
#include <hip/hip_bf16.h>
#include <cstdint>
#include <cstddef>

#define DDIM 1024
#define BROWS 32768

typedef __attribute__((ext_vector_type(8))) short short8;
typedef __attribute__((ext_vector_type(4))) float floatx4;

__device__ __forceinline__ float bf2f(unsigned short u) {
  return __uint_as_float(((unsigned int)u) << 16);
}
__device__ __forceinline__ unsigned short f2bf(float f) {
  unsigned int u = __float_as_uint(f);
  u += 0x7FFFu + ((u >> 16) & 1u);
  return (unsigned short)(u >> 16);
}

__device__ __forceinline__ void load_lds16(const void* g, void* l) {
  __builtin_amdgcn_global_load_lds(
      (const __attribute__((address_space(1))) unsigned int*)g,
      (__attribute__((address_space(3))) unsigned int*)l,
      16, 0, 0);
}

// ===========================================================================
// Big GEMM: Out = (x @ W) * inv + bias.
// EXACTLY round-1's main loop (serial 2-barrier staging, natural block order,
// measured 3.84 TB/s) + round-2's LDS epilogue (measured ideal WRITE=131MB).
// ===========================================================================
__global__ void __launch_bounds__(256, 4)
big_gemm(const float* __restrict__ Af, const unsigned short* __restrict__ Bt,
         float* __restrict__ Outf, const float* __restrict__ inv_ptr,
         const float* __restrict__ bias)
{
  __shared__ __align__(16) char smem[16896];
  unsigned short* As = (unsigned short*)smem;          // 8 KB
  unsigned short* Bs = (unsigned short*)(smem + 8192); // 8 KB
  float* epi = (float*)smem;                           // epilogue alias

  const int tid  = threadIdx.x;
  const int lane = tid & 63;
  const int wid  = tid >> 6;
  const int wr = wid >> 1, wc = wid & 1;
  const int g = lane >> 4, r = lane & 15;

  const int bn0 = (int)(blockIdx.x & 7) * 128;
  const int bm0 = (int)(blockIdx.x >> 3) * 128;

  const floatx4 zero4 = {0.f, 0.f, 0.f, 0.f};
  floatx4 acc[4][4];
#pragma unroll
  for (int m = 0; m < 4; ++m)
#pragma unroll
    for (int n = 0; n < 4; ++n) acc[m][n] = zero4;

  for (int kk = 0; kk < DDIM; kk += 32) {
    __syncthreads();
    // stage B tile (bf16, async direct-to-LDS)
#pragma unroll
    for (int p = 0; p < 2; ++p) {
      const int o = p * 4096 + tid * 16;  // byte offset in tile
      const int row = o >> 6;             // 64B per row (32 bf16)
      const int cole = (o & 63) >> 1;     // element col (0,8,16,24)
      load_lds16(Bt + (size_t)(bn0 + row) * DDIM + kk + cole, (char*)Bs + o);
    }
    // stage A tile: f32 -> bf16 reg-convert
#pragma unroll
    for (int p = 0; p < 2; ++p) {
      const int o = p * 4096 + tid * 16;
      const int row = o >> 6;
      const int cole = (o & 63) >> 1;
      const float4* s = (const float4*)(Af + (size_t)(bm0 + row) * DDIM + kk + cole);
      float4 x0 = s[0], x1 = s[1];
      short8 t;
      t[0] = (short)f2bf(x0.x); t[1] = (short)f2bf(x0.y);
      t[2] = (short)f2bf(x0.z); t[3] = (short)f2bf(x0.w);
      t[4] = (short)f2bf(x1.x); t[5] = (short)f2bf(x1.y);
      t[6] = (short)f2bf(x1.z); t[7] = (short)f2bf(x1.w);
      *(short8*)((char*)As + o) = t;
    }
    __syncthreads();

    short8 afr[4], bfr[4];
#pragma unroll
    for (int m = 0; m < 4; ++m)
      afr[m] = *(const short8*)((const char*)As + (wr * 64 + m * 16 + r) * 64 + g * 16);
#pragma unroll
    for (int n = 0; n < 4; ++n)
      bfr[n] = *(const short8*)((const char*)Bs + (wc * 64 + n * 16 + r) * 64 + g * 16);
#pragma unroll
    for (int m = 0; m < 4; ++m)
#pragma unroll
      for (int n = 0; n < 4; ++n)
        acc[m][n] = __builtin_amdgcn_mfma_f32_16x16x32_bf16(afr[m], bfr[n], acc[m][n], 0, 0, 0);
  }

  // Epilogue: stage 32x128 f32 chunks in LDS, store 64B/thread contiguous.
  const float inv = *inv_ptr;
  float bv[4];
#pragma unroll
  for (int n = 0; n < 4; ++n) bv[n] = bias[bn0 + wc * 64 + n * 16 + r];

#pragma unroll
  for (int m = 0; m < 4; ++m) {
    __syncthreads();
#pragma unroll
    for (int n = 0; n < 4; ++n)
#pragma unroll
      for (int q = 0; q < 4; ++q)
        epi[(wr * 16 + g * 4 + q) * 132 + wc * 64 + n * 16 + r] =
            acc[m][n][q] * inv + bv[n];
    __syncthreads();
    const int lrow = tid >> 3;            // 0..31
    const int lc0  = (tid & 7) * 16;      // 16 floats per thread
    const int grow = bm0 + m * 16 + (lrow & 15) + (lrow >> 4) * 64;
    float4* dst = (float4*)(Outf + (size_t)grow * DDIM + bn0 + lc0);
    const float4* sv = (const float4*)(epi + lrow * 132 + lc0);
    dst[0] = sv[0]; dst[1] = sv[1]; dst[2] = sv[2]; dst[3] = sv[3];
  }
}

// ===========================================================================
// Small square GEMM (1024^3): C[i][j] = sum_k A[i][k]*Bt[j][k], bf16 in/out.
// 32x32 tiles, BK=64, double-buffered global_load_lds, XOR-swizzled reads.
// (unchanged from round 2 — verified correct, not a bottleneck)
// ===========================================================================
__global__ void __launch_bounds__(256, 4)
sq_gemm(const unsigned short* __restrict__ A, const unsigned short* __restrict__ Bt,
        unsigned short* __restrict__ Out, const float* __restrict__ in_max,
        float* __restrict__ out_max)
{
  __shared__ __align__(16) unsigned short As[2][2048];
  __shared__ __align__(16) unsigned short Bs[2][2048];
  __shared__ float redw[4];

  const int tid  = threadIdx.x;
  const int lane = tid & 63;
  const int wid  = tid >> 6;
  const int wr = wid >> 1, wc = wid & 1;
  const int g = lane >> 4, r = lane & 15;

  const int bm0 = (int)(blockIdx.x >> 5) * 32;
  const int bn0 = (int)(blockIdx.x & 31) * 32;

  const int so   = tid * 16;
  const int srow = so >> 7;
  const int sc16 = (so >> 4) & 7;
  const int scs  = sc16 ^ (srow & 7);
  const unsigned short* aSrc = A  + (size_t)(bm0 + srow) * DDIM + scs * 8;
  const unsigned short* bSrc = Bt + (size_t)(bn0 + srow) * DDIM + scs * 8;

  floatx4 acc = {0.f, 0.f, 0.f, 0.f};

  load_lds16(aSrc, (char*)&As[0][0] + so);
  load_lds16(bSrc, (char*)&Bs[0][0] + so);
  __syncthreads();

  const int arow = wr * 16 + r;
  const int brow = wc * 16 + r;
  int buf = 0;
  for (int t = 0; t < 16; ++t) {
    if (t + 1 < 16) {
      const int kk = (t + 1) * 64;
      load_lds16(aSrc + kk, (char*)&As[buf ^ 1][0] + so);
      load_lds16(bSrc + kk, (char*)&Bs[buf ^ 1][0] + so);
    }
#pragma unroll
    for (int ks = 0; ks < 2; ++ks) {
      const int chunk = ((ks << 2) + g) ^ (r & 7);
      short8 af = *(const short8*)((const char*)&As[buf][0] + (arow << 7) + (chunk << 4));
      short8 bf = *(const short8*)((const char*)&Bs[buf][0] + (brow << 7) + (chunk << 4));
      acc = __builtin_amdgcn_mfma_f32_16x16x32_bf16(af, bf, acc, 0, 0, 0);
    }
    __syncthreads();
    buf ^= 1;
  }

  float c = 1.0f;
  if (in_max != nullptr) {
    int e;
    (void)frexpf(*in_max, &e);
    c = ldexpf(1.0f, -e);  // exact power of two
  }
  const float c2 = c * c;
  float lmax = 0.0f;
  const int ocol = bn0 + wc * 16 + r;
#pragma unroll
  for (int q = 0; q < 4; ++q) {
    const int orow = bm0 + wr * 16 + g * 4 + q;
    float v = acc[q] * c2;
    Out[(size_t)orow * DDIM + ocol] = f2bf(v);
    lmax = fmaxf(lmax, fabsf(v));
  }
#pragma unroll
  for (int off = 32; off > 0; off >>= 1) lmax = fmaxf(lmax, __shfl_down(lmax, off));
  if (lane == 0) redw[wid] = lmax;
  __syncthreads();
  if (tid == 0) {
    float m = fmaxf(fmaxf(redw[0], redw[1]), fmaxf(redw[2], redw[3]));
    atomicMax((unsigned int*)out_max, __float_as_uint(m));
  }
}

// WT[n][k] = bf16(W[k][n])
__global__ void __launch_bounds__(256)
transpose_bf16(const float* __restrict__ W, unsigned short* __restrict__ WT)
{
  __shared__ float tile[64][65];
  const int bx = blockIdx.x & 15;
  const int by = blockIdx.x >> 4;
  const int tid = threadIdx.x;
  const int c = tid & 63;
  const int r0 = tid >> 6;
#pragma unroll
  for (int p = 0; p < 16; ++p) {
    int kr = p * 4 + r0;
    tile[kr][c] = W[(size_t)(bx * 64 + kr) * DDIM + by * 64 + c];
  }
  __syncthreads();
#pragma unroll
  for (int p = 0; p < 16; ++p) {
    int nr = p * 4 + r0;
    WT[(size_t)(by * 64 + nr) * DDIM + bx * 64 + c] = f2bf(tile[c][nr]);
  }
}

// vout[j] = 2^-12 * sum_i vin[i] * P[j][i]   (P symmetric bf16 1024x1024)
__global__ void __launch_bounds__(256)
gemv_pow(const unsigned short* __restrict__ P, const float* __restrict__ vin,
         float* __restrict__ vout)
{
  const int tid = threadIdx.x;
  const int lane = tid & 63;
  const int wid = tid >> 6;
  float vs[16];
  const float4* vv = (const float4*)(vin + lane * 16);
#pragma unroll
  for (int i = 0; i < 4; ++i) {
    float4 t = vv[i];
    vs[i * 4 + 0] = t.x; vs[i * 4 + 1] = t.y; vs[i * 4 + 2] = t.z; vs[i * 4 + 3] = t.w;
  }
#pragma unroll
  for (int rr = 0; rr < 4; ++rr) {
    const int row = (int)blockIdx.x * 16 + wid * 4 + rr;
    const unsigned short* pr = P + (size_t)row * DDIM + lane * 16;
    short8 p0 = *(const short8*)pr;
    short8 p1 = *(const short8*)(pr + 8);
    float s = 0.f;
#pragma unroll
    for (int e = 0; e < 8; ++e) s += bf2f((unsigned short)p0[e]) * vs[e];
#pragma unroll
    for (int e = 0; e < 8; ++e) s += bf2f((unsigned short)p1[e]) * vs[8 + e];
#pragma unroll
    for (int off = 32; off > 0; off >>= 1) s += __shfl_down(s, off);
    if (lane == 0) vout[row] = s * 0x1p-12f;
  }
}

// v_un[i] = sum_j d[j] * W[i][j]; per-block ssq partial -> vpart[bid]
__global__ void __launch_bounds__(256)
v_kernel(const float* __restrict__ W, const float* __restrict__ d,
         float* __restrict__ v_un, float* __restrict__ vpart)
{
  __shared__ float wsum[4];
  const int tid = threadIdx.x;
  const int lane = tid & 63;
  const int wid = tid >> 6;
  float vs[16];
  const float4* dv = (const float4*)(d + lane * 16);
#pragma unroll
  for (int i = 0; i < 4; ++i) {
    float4 t = dv[i];
    vs[i * 4 + 0] = t.x; vs[i * 4 + 1] = t.y; vs[i * 4 + 2] = t.z; vs[i * 4 + 3] = t.w;
  }
  float ssq = 0.f;
#pragma unroll
  for (int rr = 0; rr < 4; ++rr) {
    const int row = (int)blockIdx.x * 16 + wid * 4 + rr;
    const float4* wrow = (const float4*)(W + (size_t)row * DDIM + lane * 16);
    float s = 0.f;
#pragma unroll
    for (int i = 0; i < 4; ++i) {
      float4 t = wrow[i];
      s += t.x * vs[i * 4 + 0] + t.y * vs[i * 4 + 1] + t.z * vs[i * 4 + 2] + t.w * vs[i * 4 + 3];
    }
#pragma unroll
    for (int off = 32; off > 0; off >>= 1) s += __shfl_down(s, off);
    if (lane == 0) { v_un[row] = s; ssq += s * s; }
  }
  if (lane == 0) wsum[wid] = ssq;
  __syncthreads();
  if (tid == 0) vpart[blockIdx.x] = (wsum[0] + wsum[1]) + (wsum[2] + wsum[3]);
}

// t[j] = sum_i v_un[i]*W[i][j]; tpart[bid] = sum over this block's 32 cols of t^2
__global__ void __launch_bounds__(256)
t_kernel(const float* __restrict__ W, const float* __restrict__ v_un,
         float* __restrict__ tpart)
{
  __shared__ float part[8][33];
  const int tid = threadIdx.x;
  const int col = (int)blockIdx.x * 32 + (tid & 31);
  const int ch = tid >> 5;
  float s = 0.f;
  const int i0 = ch * 128;
  for (int i = i0; i < i0 + 128; ++i)
    s += v_un[i] * W[(size_t)i * DDIM + col];
  part[ch][tid & 31] = s;
  __syncthreads();
  if (tid < 32) {
    float t = 0.f;
#pragma unroll
    for (int c2 = 0; c2 < 8; ++c2) t += part[c2][tid];
    part[0][tid] = t * t;
  }
  __syncthreads();
  if (tid == 0) {
    float ss = 0.f;
#pragma unroll
    for (int c = 0; c < 32; ++c) ss += part[0][c];
    tpart[blockIdx.x] = ss;
  }
}

__global__ void finalize_kernel(const float* __restrict__ vpart,
                                const float* __restrict__ tpart,
                                float* __restrict__ inv_out)
{
  float sv = 0.f, st = 0.f;
  for (int i = 0; i < 64; ++i) sv += vpart[i];
  for (int i = 0; i < 32; ++i) st += tpart[i];
  float sigma = sqrtf(st / sv);
  inv_out[0] = (sigma > 0.9f) ? (0.9f / sigma) : 1.0f;
}

extern "C" void kernel_launch(void* const* d_in, const int* in_sizes, int n_in,
                              void* d_out, int out_size, void* d_ws, size_t ws_size,
                              hipStream_t stream)
{
  const float* x  = (const float*)d_in[0];
  const float* w  = (const float*)d_in[1];
  const float* b  = (const float*)d_in[2];
  const float* u0 = (const float*)d_in[3];
  float* out = (float*)d_out;

  char* ws = (char*)d_ws;
  float* scal = (float*)ws;  // [0..5] max chain, [8] inv, [16..79] vpart, [80..111] tpart
  float* u_a  = (float*)(ws + 0x1000);
  float* u_b  = (float*)(ws + 0x2000);
  float* v_un = (float*)(ws + 0x3000);
  unsigned short* WT = (unsigned short*)(ws + 0x4000);
  unsigned short* P0 = (unsigned short*)(ws + 0x204000);
  unsigned short* P1 = (unsigned short*)(ws + 0x404000);

  hipMemsetAsync(d_ws, 0, 4096, stream);
  hipLaunchKernelGGL(transpose_bf16, dim3(256), dim3(256), 0, stream, w, WT);

  // M = W^T W, then square up to M^32
  hipLaunchKernelGGL(sq_gemm, dim3(1024), dim3(256), 0, stream,
                     WT, WT, P0, (const float*)nullptr, &scal[0]);          // M
  hipLaunchKernelGGL(sq_gemm, dim3(1024), dim3(256), 0, stream,
                     P0, P0, P1, &scal[0], &scal[1]);                       // M^2
  hipLaunchKernelGGL(sq_gemm, dim3(1024), dim3(256), 0, stream,
                     P1, P1, P0, &scal[1], &scal[2]);                       // M^4
  hipLaunchKernelGGL(sq_gemm, dim3(1024), dim3(256), 0, stream,
                     P0, P0, P1, &scal[2], &scal[3]);                       // M^8
  hipLaunchKernelGGL(sq_gemm, dim3(1024), dim3(256), 0, stream,
                     P1, P1, P0, &scal[3], &scal[4]);                       // M^16
  hipLaunchKernelGGL(sq_gemm, dim3(1024), dim3(256), 0, stream,
                     P0, P0, P1, &scal[4], &scal[5]);                       // M^32 -> P1

  // u = u0 * (M^32)^3  (direction of u0 M^96)
  hipLaunchKernelGGL(gemv_pow, dim3(64), dim3(256), 0, stream, P1, u0, u_a);
  hipLaunchKernelGGL(gemv_pow, dim3(64), dim3(256), 0, stream, P1, u_a, u_b);
  hipLaunchKernelGGL(gemv_pow, dim3(64), dim3(256), 0, stream, P1, u_b, u_a);

  hipLaunchKernelGGL(v_kernel, dim3(64), dim3(256), 0, stream, w, u_a, v_un, &scal[16]);
  hipLaunchKernelGGL(t_kernel, dim3(32), dim3(256), 0, stream, w, v_un, &scal[80]);
  hipLaunchKernelGGL(finalize_kernel, dim3(1), dim3(1), 0, stream,
                     &scal[16], &scal[80], &scal[8]);

  // out = (x @ W) * inv + b
  hipLaunchKernelGGL(big_gemm, dim3(2048), dim3(256), 0, stream,
                     x, WT, out, &scal[8], b);
}

// Round 5
// 303.968 us; speedup vs baseline: 4.7336x; 1.1211x over previous
//
#include <hip/hip_runtime.h>
#include <hip/hip_bf16.h>
#include <cstdint>
#include <cstddef>

#define DDIM 1024
#define BROWS 32768

typedef __attribute__((ext_vector_type(8))) short short8;
typedef __attribute__((ext_vector_type(4))) float floatx4;

__device__ __forceinline__ float bf2f(unsigned short u) {
  return __uint_as_float(((unsigned int)u) << 16);
}
__device__ __forceinline__ unsigned short f2bf(float f) {
  unsigned int u = __float_as_uint(f);
  u += 0x7FFFu + ((u >> 16) & 1u);
  return (unsigned short)(u >> 16);
}

__device__ __forceinline__ void load_lds16(const void* g, void* l) {
  __builtin_amdgcn_global_load_lds(
      (const __attribute__((address_space(1))) unsigned int*)g,
      (__attribute__((address_space(3))) unsigned int*)l,
      16, 0, 0);
}

// ===========================================================================
// Big GEMM: Out = (x @ W) * inv + bias.
// R3's double-buffered main loop (A: f32 reg-prefetch + cvt; B: async
// global_load_lds) + R2's XCD-aware swizzle (A-panel pinned to one XCD's L2,
// FETCH measured 93 MB) + LDS epilogue (WRITE measured 131 MB ideal).
// ===========================================================================
__global__ void __launch_bounds__(256, 2)
big_gemm(const float* __restrict__ Af, const unsigned short* __restrict__ Bt,
         float* __restrict__ Outf, const float* __restrict__ inv_ptr,
         const float* __restrict__ bias)
{
  __shared__ __align__(16) char smem[33280];
  // As buffers: [0,8192), [8192,16384); Bs buffers: [16384,24576), [24576,32768)
  float* epi = (float*)smem;  // epilogue alias, 16896 B

  const int tid  = threadIdx.x;
  const int lane = tid & 63;
  const int wid  = tid >> 6;
  const int wr = wid >> 1, wc = wid & 1;
  const int g = lane >> 4, r = lane & 15;

  // XCD-aware swizzle: 2048 blocks round-robin over 8 XCDs; give XCD x the
  // contiguous tile range [x*256, x*256+256) = 32 m-panels x 8 n-tiles, so an
  // A-panel's 8 consumers all run on ONE XCD and share its L2.
  const int swz = (int)((blockIdx.x & 7) * 256 + (blockIdx.x >> 3));
  const int bn0 = (swz & 7) * 128;
  const int bm0 = (swz >> 3) * 128;

  // staging geometry: thread covers (row = strow [+64], cols stcol..stcol+7)
  const int strow = tid >> 2;
  const int stcol = (tid & 3) * 8;
  const float* aB0 = Af + (size_t)(bm0 + strow) * DDIM + stcol;
  const float* aB1 = Af + (size_t)(bm0 + 64 + strow) * DDIM + stcol;
  const unsigned short* bB0 = Bt + (size_t)(bn0 + strow) * DDIM + stcol;
  const unsigned short* bB1 = Bt + (size_t)(bn0 + 64 + strow) * DDIM + stcol;

  const floatx4 zero4 = {0.f, 0.f, 0.f, 0.f};
  floatx4 acc[4][4];
#pragma unroll
  for (int m = 0; m < 4; ++m)
#pragma unroll
    for (int n = 0; n < 4; ++n) acc[m][n] = zero4;

  // prologue: stage K-tile 0 into buffer 0
  {
    load_lds16(bB0, smem + 16384 + tid * 16);
    load_lds16(bB1, smem + 16384 + 4096 + tid * 16);
    float4 n0 = *(const float4*)aB0;
    float4 n1 = *(const float4*)(aB0 + 4);
    float4 n2 = *(const float4*)aB1;
    float4 n3 = *(const float4*)(aB1 + 4);
    short8 t0, t1;
    t0[0] = (short)f2bf(n0.x); t0[1] = (short)f2bf(n0.y);
    t0[2] = (short)f2bf(n0.z); t0[3] = (short)f2bf(n0.w);
    t0[4] = (short)f2bf(n1.x); t0[5] = (short)f2bf(n1.y);
    t0[6] = (short)f2bf(n1.z); t0[7] = (short)f2bf(n1.w);
    t1[0] = (short)f2bf(n2.x); t1[1] = (short)f2bf(n2.y);
    t1[2] = (short)f2bf(n2.z); t1[3] = (short)f2bf(n2.w);
    t1[4] = (short)f2bf(n3.x); t1[5] = (short)f2bf(n3.y);
    t1[6] = (short)f2bf(n3.z); t1[7] = (short)f2bf(n3.w);
    *(short8*)(smem + tid * 16) = t0;
    *(short8*)(smem + 4096 + tid * 16) = t1;
  }
  __syncthreads();

  for (int t = 0; t < 32; ++t) {
    const int co = (t & 1) << 13;  // 0 / 8192
    char* curA = smem + co;
    char* curB = smem + 16384 + co;
    char* nxtA = smem + (co ^ 8192);
    char* nxtB = smem + 16384 + (co ^ 8192);

    float4 n0, n1, n2, n3;
    const bool pref = (t < 31);
    if (pref) {
      const int ko = (t + 1) * 32;
      n0 = *(const float4*)(aB0 + ko);  // issued early, consumed late
      n1 = *(const float4*)(aB0 + ko + 4);
      n2 = *(const float4*)(aB1 + ko);
      n3 = *(const float4*)(aB1 + ko + 4);
      load_lds16(bB0 + ko, nxtB + tid * 16);
      load_lds16(bB1 + ko, nxtB + 4096 + tid * 16);
    }

    short8 afr[4], bfr[4];
#pragma unroll
    for (int m = 0; m < 4; ++m)
      afr[m] = *(const short8*)(curA + (wr * 64 + m * 16 + r) * 64 + g * 16);
#pragma unroll
    for (int n = 0; n < 4; ++n)
      bfr[n] = *(const short8*)(curB + (wc * 64 + n * 16 + r) * 64 + g * 16);
#pragma unroll
    for (int m = 0; m < 4; ++m)
#pragma unroll
      for (int n = 0; n < 4; ++n)
        acc[m][n] = __builtin_amdgcn_mfma_f32_16x16x32_bf16(afr[m], bfr[n], acc[m][n], 0, 0, 0);

    if (pref) {
      short8 t0, t1;
      t0[0] = (short)f2bf(n0.x); t0[1] = (short)f2bf(n0.y);
      t0[2] = (short)f2bf(n0.z); t0[3] = (short)f2bf(n0.w);
      t0[4] = (short)f2bf(n1.x); t0[5] = (short)f2bf(n1.y);
      t0[6] = (short)f2bf(n1.z); t0[7] = (short)f2bf(n1.w);
      t1[0] = (short)f2bf(n2.x); t1[1] = (short)f2bf(n2.y);
      t1[2] = (short)f2bf(n2.z); t1[3] = (short)f2bf(n2.w);
      t1[4] = (short)f2bf(n3.x); t1[5] = (short)f2bf(n3.y);
      t1[6] = (short)f2bf(n3.z); t1[7] = (short)f2bf(n3.w);
      *(short8*)(nxtA + tid * 16) = t0;
      *(short8*)(nxtA + 4096 + tid * 16) = t1;
    }
    __syncthreads();  // drains gload_lds (nxtB) + ds_writes (nxtA)
  }

  // Epilogue: stage 32x128 f32 chunks in LDS, store 64B/thread contiguous.
  const float inv = *inv_ptr;
  float bv[4];
#pragma unroll
  for (int n = 0; n < 4; ++n) bv[n] = bias[bn0 + wc * 64 + n * 16 + r];

#pragma unroll
  for (int m = 0; m < 4; ++m) {
    __syncthreads();
#pragma unroll
    for (int n = 0; n < 4; ++n)
#pragma unroll
      for (int q = 0; q < 4; ++q)
        epi[(wr * 16 + g * 4 + q) * 132 + wc * 64 + n * 16 + r] =
            acc[m][n][q] * inv + bv[n];
    __syncthreads();
    const int lrow = tid >> 3;
    const int lc0  = (tid & 7) * 16;
    const int grow = bm0 + m * 16 + (lrow & 15) + (lrow >> 4) * 64;
    float4* dst = (float4*)(Outf + (size_t)grow * DDIM + bn0 + lc0);
    const float4* sv = (const float4*)(epi + lrow * 132 + lc0);
    dst[0] = sv[0]; dst[1] = sv[1]; dst[2] = sv[2]; dst[3] = sv[3];
  }
}

// ===========================================================================
// Small square GEMM (1024^3), unchanged (verified, not the bottleneck).
// ===========================================================================
__global__ void __launch_bounds__(256, 4)
sq_gemm(const unsigned short* __restrict__ A, const unsigned short* __restrict__ Bt,
        unsigned short* __restrict__ Out, const float* __restrict__ in_max,
        float* __restrict__ out_max)
{
  __shared__ __align__(16) unsigned short As[2][2048];
  __shared__ __align__(16) unsigned short Bs[2][2048];
  __shared__ float redw[4];

  const int tid  = threadIdx.x;
  const int lane = tid & 63;
  const int wid  = tid >> 6;
  const int wr = wid >> 1, wc = wid & 1;
  const int g = lane >> 4, r = lane & 15;

  const int bm0 = (int)(blockIdx.x >> 5) * 32;
  const int bn0 = (int)(blockIdx.x & 31) * 32;

  const int so   = tid * 16;
  const int srow = so >> 7;
  const int sc16 = (so >> 4) & 7;
  const int scs  = sc16 ^ (srow & 7);
  const unsigned short* aSrc = A  + (size_t)(bm0 + srow) * DDIM + scs * 8;
  const unsigned short* bSrc = Bt + (size_t)(bn0 + srow) * DDIM + scs * 8;

  floatx4 acc = {0.f, 0.f, 0.f, 0.f};

  load_lds16(aSrc, (char*)&As[0][0] + so);
  load_lds16(bSrc, (char*)&Bs[0][0] + so);
  __syncthreads();

  const int arow = wr * 16 + r;
  const int brow = wc * 16 + r;
  int buf = 0;
  for (int t = 0; t < 16; ++t) {
    if (t + 1 < 16) {
      const int kk = (t + 1) * 64;
      load_lds16(aSrc + kk, (char*)&As[buf ^ 1][0] + so);
      load_lds16(bSrc + kk, (char*)&Bs[buf ^ 1][0] + so);
    }
#pragma unroll
    for (int ks = 0; ks < 2; ++ks) {
      const int chunk = ((ks << 2) + g) ^ (r & 7);
      short8 af = *(const short8*)((const char*)&As[buf][0] + (arow << 7) + (chunk << 4));
      short8 bf = *(const short8*)((const char*)&Bs[buf][0] + (brow << 7) + (chunk << 4));
      acc = __builtin_amdgcn_mfma_f32_16x16x32_bf16(af, bf, acc, 0, 0, 0);
    }
    __syncthreads();
    buf ^= 1;
  }

  float c = 1.0f;
  if (in_max != nullptr) {
    int e;
    (void)frexpf(*in_max, &e);
    c = ldexpf(1.0f, -e);  // exact power of two
  }
  const float c2 = c * c;
  float lmax = 0.0f;
  const int ocol = bn0 + wc * 16 + r;
#pragma unroll
  for (int q = 0; q < 4; ++q) {
    const int orow = bm0 + wr * 16 + g * 4 + q;
    float v = acc[q] * c2;
    Out[(size_t)orow * DDIM + ocol] = f2bf(v);
    lmax = fmaxf(lmax, fabsf(v));
  }
#pragma unroll
  for (int off = 32; off > 0; off >>= 1) lmax = fmaxf(lmax, __shfl_down(lmax, off));
  if (lane == 0) redw[wid] = lmax;
  __syncthreads();
  if (tid == 0) {
    float m = fmaxf(fmaxf(redw[0], redw[1]), fmaxf(redw[2], redw[3]));
    atomicMax((unsigned int*)out_max, __float_as_uint(m));
  }
}

// WT[n][k] = bf16(W[k][n])
__global__ void __launch_bounds__(256)
transpose_bf16(const float* __restrict__ W, unsigned short* __restrict__ WT)
{
  __shared__ float tile[64][65];
  const int bx = blockIdx.x & 15;
  const int by = blockIdx.x >> 4;
  const int tid = threadIdx.x;
  const int c = tid & 63;
  const int r0 = tid >> 6;
#pragma unroll
  for (int p = 0; p < 16; ++p) {
    int kr = p * 4 + r0;
    tile[kr][c] = W[(size_t)(bx * 64 + kr) * DDIM + by * 64 + c];
  }
  __syncthreads();
#pragma unroll
  for (int p = 0; p < 16; ++p) {
    int nr = p * 4 + r0;
    WT[(size_t)(by * 64 + nr) * DDIM + bx * 64 + c] = f2bf(tile[c][nr]);
  }
}

// vout[j] = 2^-12 * sum_i vin[i] * P[j][i]   (P symmetric bf16 1024x1024)
__global__ void __launch_bounds__(256)
gemv_pow(const unsigned short* __restrict__ P, const float* __restrict__ vin,
         float* __restrict__ vout)
{
  const int tid = threadIdx.x;
  const int lane = tid & 63;
  const int wid = tid >> 6;
  float vs[16];
  const float4* vv = (const float4*)(vin + lane * 16);
#pragma unroll
  for (int i = 0; i < 4; ++i) {
    float4 t = vv[i];
    vs[i * 4 + 0] = t.x; vs[i * 4 + 1] = t.y; vs[i * 4 + 2] = t.z; vs[i * 4 + 3] = t.w;
  }
#pragma unroll
  for (int rr = 0; rr < 4; ++rr) {
    const int row = (int)blockIdx.x * 16 + wid * 4 + rr;
    const unsigned short* pr = P + (size_t)row * DDIM + lane * 16;
    short8 p0 = *(const short8*)pr;
    short8 p1 = *(const short8*)(pr + 8);
    float s = 0.f;
#pragma unroll
    for (int e = 0; e < 8; ++e) s += bf2f((unsigned short)p0[e]) * vs[e];
#pragma unroll
    for (int e = 0; e < 8; ++e) s += bf2f((unsigned short)p1[e]) * vs[8 + e];
#pragma unroll
    for (int off = 32; off > 0; off >>= 1) s += __shfl_down(s, off);
    if (lane == 0) vout[row] = s * 0x1p-12f;
  }
}

// v_un[i] = sum_j d[j] * W[i][j]; per-block ssq partial -> vpart[bid]
__global__ void __launch_bounds__(256)
v_kernel(const float* __restrict__ W, const float* __restrict__ d,
         float* __restrict__ v_un, float* __restrict__ vpart)
{
  __shared__ float wsum[4];
  const int tid = threadIdx.x;
  const int lane = tid & 63;
  const int wid = tid >> 6;
  float vs[16];
  const float4* dv = (const float4*)(d + lane * 16);
#pragma unroll
  for (int i = 0; i < 4; ++i) {
    float4 t = dv[i];
    vs[i * 4 + 0] = t.x; vs[i * 4 + 1] = t.y; vs[i * 4 + 2] = t.z; vs[i * 4 + 3] = t.w;
  }
  float ssq = 0.f;
#pragma unroll
  for (int rr = 0; rr < 4; ++rr) {
    const int row = (int)blockIdx.x * 16 + wid * 4 + rr;
    const float4* wrow = (const float4*)(W + (size_t)row * DDIM + lane * 16);
    float s = 0.f;
#pragma unroll
    for (int i = 0; i < 4; ++i) {
      float4 t = wrow[i];
      s += t.x * vs[i * 4 + 0] + t.y * vs[i * 4 + 1] + t.z * vs[i * 4 + 2] + t.w * vs[i * 4 + 3];
    }
#pragma unroll
    for (int off = 32; off > 0; off >>= 1) s += __shfl_down(s, off);
    if (lane == 0) { v_un[row] = s; ssq += s * s; }
  }
  if (lane == 0) wsum[wid] = ssq;
  __syncthreads();
  if (tid == 0) vpart[blockIdx.x] = (wsum[0] + wsum[1]) + (wsum[2] + wsum[3]);
}

// t[j] = sum_i v_un[i]*W[i][j]; tpart[bid] = sum over this block's 32 cols of t^2
__global__ void __launch_bounds__(256)
t_kernel(const float* __restrict__ W, const float* __restrict__ v_un,
         float* __restrict__ tpart)
{
  __shared__ float part[8][33];
  const int tid = threadIdx.x;
  const int col = (int)blockIdx.x * 32 + (tid & 31);
  const int ch = tid >> 5;
  float s = 0.f;
  const int i0 = ch * 128;
  for (int i = i0; i < i0 + 128; ++i)
    s += v_un[i] * W[(size_t)i * DDIM + col];
  part[ch][tid & 31] = s;
  __syncthreads();
  if (tid < 32) {
    float t = 0.f;
#pragma unroll
    for (int c2 = 0; c2 < 8; ++c2) t += part[c2][tid];
    part[0][tid] = t * t;
  }
  __syncthreads();
  if (tid == 0) {
    float ss = 0.f;
#pragma unroll
    for (int c = 0; c < 32; ++c) ss += part[0][c];
    tpart[blockIdx.x] = ss;
  }
}

__global__ void finalize_kernel(const float* __restrict__ vpart,
                                const float* __restrict__ tpart,
                                float* __restrict__ inv_out)
{
  float sv = 0.f, st = 0.f;
  for (int i = 0; i < 64; ++i) sv += vpart[i];
  for (int i = 0; i < 32; ++i) st += tpart[i];
  float sigma = sqrtf(st / sv);
  inv_out[0] = (sigma > 0.9f) ? (0.9f / sigma) : 1.0f;
}

extern "C" void kernel_launch(void* const* d_in, const int* in_sizes, int n_in,
                              void* d_out, int out_size, void* d_ws, size_t ws_size,
                              hipStream_t stream)
{
  const float* x  = (const float*)d_in[0];
  const float* w  = (const float*)d_in[1];
  const float* b  = (const float*)d_in[2];
  const float* u0 = (const float*)d_in[3];
  float* out = (float*)d_out;

  char* ws = (char*)d_ws;
  float* scal = (float*)ws;  // [0..5] max chain, [8] inv, [16..79] vpart, [80..111] tpart
  float* u_a  = (float*)(ws + 0x1000);
  float* u_b  = (float*)(ws + 0x2000);
  float* v_un = (float*)(ws + 0x3000);
  unsigned short* WT = (unsigned short*)(ws + 0x4000);
  unsigned short* P0 = (unsigned short*)(ws + 0x204000);
  unsigned short* P1 = (unsigned short*)(ws + 0x404000);

  hipMemsetAsync(d_ws, 0, 4096, stream);
  hipLaunchKernelGGL(transpose_bf16, dim3(256), dim3(256), 0, stream, w, WT);

  // M = W^T W, then square up to M^32
  hipLaunchKernelGGL(sq_gemm, dim3(1024), dim3(256), 0, stream,
                     WT, WT, P0, (const float*)nullptr, &scal[0]);          // M
  hipLaunchKernelGGL(sq_gemm, dim3(1024), dim3(256), 0, stream,
                     P0, P0, P1, &scal[0], &scal[1]);                       // M^2
  hipLaunchKernelGGL(sq_gemm, dim3(1024), dim3(256), 0, stream,
                     P1, P1, P0, &scal[1], &scal[2]);                       // M^4
  hipLaunchKernelGGL(sq_gemm, dim3(1024), dim3(256), 0, stream,
                     P0, P0, P1, &scal[2], &scal[3]);                       // M^8
  hipLaunchKernelGGL(sq_gemm, dim3(1024), dim3(256), 0, stream,
                     P1, P1, P0, &scal[3], &scal[4]);                       // M^16
  hipLaunchKernelGGL(sq_gemm, dim3(1024), dim3(256), 0, stream,
                     P0, P0, P1, &scal[4], &scal[5]);                       // M^32 -> P1

  // u = u0 * (M^32)^3  (direction of u0 M^96)
  hipLaunchKernelGGL(gemv_pow, dim3(64), dim3(256), 0, stream, P1, u0, u_a);
  hipLaunchKernelGGL(gemv_pow, dim3(64), dim3(256), 0, stream, P1, u_a, u_b);
  hipLaunchKernelGGL(gemv_pow, dim3(64), dim3(256), 0, stream, P1, u_b, u_a);

  hipLaunchKernelGGL(v_kernel, dim3(64), dim3(256), 0, stream, w, u_a, v_un, &scal[16]);
  hipLaunchKernelGGL(t_kernel, dim3(32), dim3(256), 0, stream, w, v_un, &scal[80]);
  hipLaunchKernelGGL(finalize_kernel, dim3(1), dim3(1), 0, stream,
                     &scal[16], &scal[80], &scal[8]);

  // out = (x @ W) * inv + b
  hipLaunchKernelGGL(big_gemm, dim3(2048), dim3(256), 0, stream,
                     x, WT, out, &scal[8], b);
}